// Round 5
// baseline (313.296 us; speedup 1.0000x reference)
//
#include <hip/hip_runtime.h>
#include <cstddef>
#include <cstdint>

// B=256, S=16384, R=16, N=6.
//   V_k[b,(d,e)] = sum_s z[b,s]*core_k[d,s,e]  (k=1..5) -> bf16-split MFMA GEMM
//   W[b] = V1..V5 chain; out[b,s] = sum_d c0[s,d]*W[b,d]
//
// R5: LDS-free register-fragment GEMM (R4) decomposed into 1-WAVE BLOCKS.
// R4 counters showed latency-bound (MfmaUtil 13%, VALU 24%, occ 13%): grid
// 544x4-wave blocks = ~1-2 waves/SIMD resident. Same per-wave work, grid
// 2176 1-wave blocks (+launch_bounds(64,4) -> VGPR<=128) => ~4 waves/SIMD.
namespace {
constexpr int kB = 256;
constexpr int kS = 16384;
constexpr int kNCol = 1040;   // 4 cores * 256 + 16 (core5)
}

using short8 = __attribute__((ext_vector_type(8))) short;   // 8 bf16
using f32x4  = __attribute__((ext_vector_type(4))) float;

// truncation split: x ~= hi + lo (bf16 each)
__device__ __forceinline__ void cvt8r(const float* __restrict__ x,
                                      short8& h, short8& l) {
    #pragma unroll
    for (int i = 0; i < 8; ++i) {
        uint32_t u = __float_as_uint(x[i]);
        h[i] = (short)(u >> 16);
        float r = x[i] - __uint_as_float(u & 0xffff0000u);
        l[i] = (short)(__float_as_uint(r) >> 16);
    }
}

// ---------------------------------------------------------------------------
// GEMM: vp[sk][b][col] partial of z @ G over k-chunk sk.
// grid = 68*splitk 1-wave blocks: (sk, mt, cg); wave tile 64 rows x 64 cols
// (cg==16: core5, 16 cols). fm=fn=4, 16x16x32 bf16 MFMA, 3-term split
// (hi*hi + hi*lo + lo*hi). Register prefetch of next 32-k slab under MFMA.
//   A (z):    lane(row=l&15, k=(l>>4)*8+j) -> 2 dwordx4 per fm
//   B (core): lane(col=e=l&15, k strided 16 floats) -> 8 dwords per fn
// ---------------------------------------------------------------------------
__global__ __launch_bounds__(64, 4) void fttv_gemm_reg(
    const float* __restrict__ z,
    const float* __restrict__ c1, const float* __restrict__ c2,
    const float* __restrict__ c3, const float* __restrict__ c4,
    const float* __restrict__ c5,
    float* __restrict__ vp, int kc)
{
    // bijective XCD swizzle; flat = (sk*4+mt)*17+cg so one XCD owns whole
    // sk-chunks (shared z k-slab + B k-rows -> L2 locality within XCD)
    const int nwg = gridDim.x;
    const int q = nwg >> 3, r = nwg & 7;
    const int xcd = blockIdx.x & 7, rest = blockIdx.x >> 3;
    const int vfl = (xcd < r ? xcd * (q + 1) : r * (q + 1) + (xcd - r) * q) + rest;
    const int sk = vfl / 68;
    const int rem = vfl - sk * 68;
    const int mt = rem / 17;
    const int cg = rem - mt * 17;

    const int l = threadIdx.x;     // 0..63
    const int lr = l & 15;         // frag row/col lane index
    const int lk = (l >> 4) * 8;   // frag k sub-offset
    const int row0 = mt * 64;
    const int kbeg = sk * kc;

    // A lane pointers per fm (8 consecutive floats each slab)
    const float* za[4];
    #pragma unroll
    for (int fm = 0; fm < 4; ++fm)
        za[fm] = z + (size_t)(row0 + fm * 16 + lr) * kS + kbeg + lk;

    f32x4 acc[4][4];
    #pragma unroll
    for (int i = 0; i < 4; ++i)
        #pragma unroll
        for (int j = 0; j < 4; ++j) acc[i][j] = (f32x4){0.f, 0.f, 0.f, 0.f};

    float ra[4][8];

    if (cg < 16) {
        const int ci = cg >> 2;
        const float* cp = (ci == 0 ? c1 : ci == 1 ? c2 : ci == 2 ? c3 : c4);
        const int d0 = (cg & 3) * 4;
        // B lane pointers per fn: core[d0+fn][k][e=lr], k-stride 16 floats
        const float* bpt[4];
        #pragma unroll
        for (int fn = 0; fn < 4; ++fn)
            bpt[fn] = cp + (size_t)(d0 + fn) * kS * 16
                    + (size_t)(kbeg + lk) * 16 + lr;

        float rb[4][8];
        // prologue loads (slab 0)
        #pragma unroll
        for (int fm = 0; fm < 4; ++fm) {
            *reinterpret_cast<float4*>(&ra[fm][0]) =
                *reinterpret_cast<const float4*>(za[fm]);
            *reinterpret_cast<float4*>(&ra[fm][4]) =
                *reinterpret_cast<const float4*>(za[fm] + 4);
        }
        #pragma unroll
        for (int fn = 0; fn < 4; ++fn)
            #pragma unroll
            for (int j = 0; j < 8; ++j)
                rb[fn][j] = bpt[fn][(size_t)j * 16];

        for (int kk = 0; kk < kc; kk += 32) {
            short8 ah[4], al[4], bh[4], bl[4];
            #pragma unroll
            for (int fm = 0; fm < 4; ++fm) cvt8r(ra[fm], ah[fm], al[fm]);
            #pragma unroll
            for (int fn = 0; fn < 4; ++fn) cvt8r(rb[fn], bh[fn], bl[fn]);
            if (kk + 32 < kc) {   // prefetch next slab (lands under MFMA)
                #pragma unroll
                for (int fm = 0; fm < 4; ++fm) {
                    *reinterpret_cast<float4*>(&ra[fm][0]) =
                        *reinterpret_cast<const float4*>(za[fm] + kk + 32);
                    *reinterpret_cast<float4*>(&ra[fm][4]) =
                        *reinterpret_cast<const float4*>(za[fm] + kk + 36);
                }
                #pragma unroll
                for (int fn = 0; fn < 4; ++fn)
                    #pragma unroll
                    for (int j = 0; j < 8; ++j)
                        rb[fn][j] = bpt[fn][(size_t)(kk + 32 + j) * 16];
            }
            #pragma unroll
            for (int fm = 0; fm < 4; ++fm)
                #pragma unroll
                for (int fn = 0; fn < 4; ++fn) {
                    acc[fm][fn] = __builtin_amdgcn_mfma_f32_16x16x32_bf16(
                        ah[fm], bh[fn], acc[fm][fn], 0, 0, 0);
                    acc[fm][fn] = __builtin_amdgcn_mfma_f32_16x16x32_bf16(
                        ah[fm], bl[fn], acc[fm][fn], 0, 0, 0);
                    acc[fm][fn] = __builtin_amdgcn_mfma_f32_16x16x32_bf16(
                        al[fm], bh[fn], acc[fm][fn], 0, 0, 0);
                }
        }
        // epilogue: C frag (col=l&15, row=(l>>4)*4+qq)
        #pragma unroll
        for (int fm = 0; fm < 4; ++fm)
            #pragma unroll
            for (int fn = 0; fn < 4; ++fn) {
                const int col = cg * 64 + fn * 16 + lr;
                const int brow = row0 + fm * 16 + (l >> 4) * 4;
                #pragma unroll
                for (int qq = 0; qq < 4; ++qq)
                    vp[((size_t)sk * kB + brow + qq) * kNCol + col] =
                        acc[fm][fn][qq];
            }
    } else {
        // core5 runt: 16 cols; B lane loads are 8 CONSECUTIVE floats
        const float* bpt5 = c5 + (size_t)lr * kS + kbeg + lk;
        float rb[8];
        #pragma unroll
        for (int fm = 0; fm < 4; ++fm) {
            *reinterpret_cast<float4*>(&ra[fm][0]) =
                *reinterpret_cast<const float4*>(za[fm]);
            *reinterpret_cast<float4*>(&ra[fm][4]) =
                *reinterpret_cast<const float4*>(za[fm] + 4);
        }
        *reinterpret_cast<float4*>(&rb[0]) =
            *reinterpret_cast<const float4*>(bpt5);
        *reinterpret_cast<float4*>(&rb[4]) =
            *reinterpret_cast<const float4*>(bpt5 + 4);

        for (int kk = 0; kk < kc; kk += 32) {
            short8 ah[4], al[4], bh, bl;
            #pragma unroll
            for (int fm = 0; fm < 4; ++fm) cvt8r(ra[fm], ah[fm], al[fm]);
            cvt8r(rb, bh, bl);
            if (kk + 32 < kc) {
                #pragma unroll
                for (int fm = 0; fm < 4; ++fm) {
                    *reinterpret_cast<float4*>(&ra[fm][0]) =
                        *reinterpret_cast<const float4*>(za[fm] + kk + 32);
                    *reinterpret_cast<float4*>(&ra[fm][4]) =
                        *reinterpret_cast<const float4*>(za[fm] + kk + 36);
                }
                *reinterpret_cast<float4*>(&rb[0]) =
                    *reinterpret_cast<const float4*>(bpt5 + kk + 32);
                *reinterpret_cast<float4*>(&rb[4]) =
                    *reinterpret_cast<const float4*>(bpt5 + kk + 36);
            }
            #pragma unroll
            for (int fm = 0; fm < 4; ++fm) {
                acc[fm][0] = __builtin_amdgcn_mfma_f32_16x16x32_bf16(
                    ah[fm], bh, acc[fm][0], 0, 0, 0);
                acc[fm][0] = __builtin_amdgcn_mfma_f32_16x16x32_bf16(
                    ah[fm], bl, acc[fm][0], 0, 0, 0);
                acc[fm][0] = __builtin_amdgcn_mfma_f32_16x16x32_bf16(
                    al[fm], bh, acc[fm][0], 0, 0, 0);
            }
        }
        #pragma unroll
        for (int fm = 0; fm < 4; ++fm) {
            const int col = 1024 + lr;
            const int brow = row0 + fm * 16 + (l >> 4) * 4;
            #pragma unroll
            for (int qq = 0; qq < 4; ++qq)
                vp[((size_t)sk * kB + brow + qq) * kNCol + col] = acc[fm][0][qq];
        }
    }
}

// ---------------------------------------------------------------------------
// v[b][col] = sum_sk vp[sk][b][col]; float4, fully coalesced.
__global__ void fttv_reduce(const float* __restrict__ vp, float* __restrict__ v,
                            int splitk)
{
    const int i4 = blockIdx.x * 256 + threadIdx.x;
    float4 s = make_float4(0.f, 0.f, 0.f, 0.f);
    for (int k = 0; k < splitk; ++k) {
        const float4 t = *reinterpret_cast<const float4*>(
            vp + (size_t)k * kNCol * kB + (size_t)i4 * 4);
        s.x += t.x; s.y += t.y; s.z += t.z; s.w += t.w;
    }
    *reinterpret_cast<float4*>(v + (size_t)i4 * 4) = s;
}

// W[b] = V1@V2@V3@V4@V5col; one 64-thr block per batch; v layout [b][col]
__global__ void fttv_chain(const float* __restrict__ v, float* __restrict__ w)
{
    const int b = blockIdx.x;
    const float* vb = v + (size_t)b * kNCol;
    const int lane = threadIdx.x;
    const int d = lane & 15;
    float u = vb[1024 + d];
    #pragma unroll
    for (int k = 4; k >= 1; --k) {
        float nu = 0.f;
        #pragma unroll
        for (int e = 0; e < 16; ++e) {
            const float ue = __shfl(u, e, 16);
            nu += vb[(k - 1) * 256 + d * 16 + e] * ue;
        }
        u = nu;
    }
    if (lane < 16) w[b * 16 + d] = u;
}

// out[b,s] = sum_d c0[s,d] * W[b,d]
__global__ __launch_bounds__(256) void fttv_out(
    const float* __restrict__ c0, const float* __restrict__ w,
    float* __restrict__ out)
{
    __shared__ float wl[64][16];
    const int sc = blockIdx.x & 63;
    const int bq = blockIdx.x >> 6;
    const int tid = threadIdx.x;
    const int s = sc * 256 + tid;
    float f0[16];
    #pragma unroll
    for (int q = 0; q < 4; ++q)
        *reinterpret_cast<float4*>(&f0[q * 4]) =
            *reinterpret_cast<const float4*>(c0 + (size_t)s * 16 + q * 4);
    *reinterpret_cast<float4*>(&wl[0][0] + tid * 4) =
        *reinterpret_cast<const float4*>(w + bq * 1024 + tid * 4);
    __syncthreads();
    for (int bb = 0; bb < 64; ++bb) {
        float a = 0.f;
        #pragma unroll
        for (int d = 0; d < 16; ++d) a += f0[d] * wl[bb][d];
        out[(size_t)(bq * 64 + bb) * kS + s] = a;
    }
}

// ---------------------------------------------------------------------------
extern "C" void kernel_launch(void* const* d_in, const int* in_sizes, int n_in,
                              void* d_out, int out_size, void* d_ws, size_t ws_size,
                              hipStream_t stream)
{
    (void)in_sizes; (void)n_in; (void)out_size;
    const float* z  = (const float*)d_in[0];
    const float* c0 = (const float*)d_in[1];
    const float* c1 = (const float*)d_in[2];
    const float* c2 = (const float*)d_in[3];
    const float* c3 = (const float*)d_in[4];
    const float* c4 = (const float*)d_in[5];
    const float* c5 = (const float*)d_in[6];
    float* out = (float*)d_out;
    float* ws  = (float*)d_ws;

    // ws: vp[splitk][256][1040] | v[256][1040] | w[256][16]
    int splitk = 32;
    while (splitk > 1 &&
           ((size_t)(splitk + 1) * kNCol * kB + (size_t)kB * 16) * sizeof(float) > ws_size)
        splitk >>= 1;
    const int kc = kS / splitk;   // multiple of 32 for splitk <= 512

    float* vp = ws;
    float* v  = vp + (size_t)splitk * kNCol * kB;
    float* w  = v + (size_t)kNCol * kB;

    fttv_gemm_reg<<<dim3(68 * splitk), 64, 0, stream>>>(z, c1, c2, c3, c4, c5, vp, kc);
    fttv_reduce<<<dim3(kNCol * kB / 1024), 256, 0, stream>>>(vp, v, splitk);
    fttv_chain<<<dim3(kB), 64, 0, stream>>>(v, w);
    fttv_out<<<dim3(256), 256, 0, stream>>>(c0, w, out);
}

// Round 7
// 77.434 us; speedup vs baseline: 4.0460x; 4.0460x over previous
//
#include <hip/hip_runtime.h>
#include <cstddef>
#include <cstdint>

// B=256, S=16384, R=16, N=6.
//   V_k[b,(d,e)] = sum_s z[b,s]*core_k[d,s,e]  (k=1..5): 3-term bf16-split MFMA
//   W[b] = V1..V5 chain; out[b,s] = sum_d c0[s,d]*W[b,d]
//
// R7: z pre-split into zh/zl bf16 planes stored FRAG-NATIVE
// ([rowblk][sblk][lr][8] = exactly the 16x16x32 A-fragment order), so the
// GEMM loads A as single coalesced dwordx4 of ready bf16: no LDS, no
// barriers, no A-cvt. B (cores) direct-to-reg dense stride-16 dwords,
// cvt exactly once grid-wide. 3-term split restores R2/R5 numerics
// (R6's interleave computed zh*bh+zl*bl and FAILED accuracy).
namespace {
constexpr int kB = 256;
constexpr int kS = 16384;
constexpr int kNCol = 1040;       // 4 cores * 256 + 16 (core5)
constexpr int kSB = kS / 8;       // 2048 s-blocks of 8
}

using short8 = __attribute__((ext_vector_type(8))) short;   // 8 bf16
using f32x4  = __attribute__((ext_vector_type(4))) float;

// ---------------------------------------------------------------------------
// Prepass: z[row][s] f32 -> zh/zl bf16, tiled idx = ((rowblk*kSB+sblk)*16+lr)*8
// (truncation split: x ~= hi + lo). Reads & writes fully coalesced.
// ---------------------------------------------------------------------------
__global__ __launch_bounds__(256) void fttv_split(
    const float* __restrict__ z,
    unsigned short* __restrict__ zh, unsigned short* __restrict__ zl)
{
    const int i = blockIdx.x * 256 + threadIdx.x;   // 524288 threads
    const int lr = i & 15;
    const int sblk = (i >> 4) & (kSB - 1);
    const int rowblk = i >> 15;
    const int row = rowblk * 16 + lr;
    const float* src = z + (size_t)row * kS + sblk * 8;
    float x[8];
    *reinterpret_cast<float4*>(&x[0]) = *reinterpret_cast<const float4*>(src);
    *reinterpret_cast<float4*>(&x[4]) = *reinterpret_cast<const float4*>(src + 4);
    short8 h, l;
    #pragma unroll
    for (int j = 0; j < 8; ++j) {
        const uint32_t u = __float_as_uint(x[j]);
        h[j] = (short)(u >> 16);
        const float r = x[j] - __uint_as_float(u & 0xffff0000u);
        l[j] = (short)(__float_as_uint(r) >> 16);
    }
    const size_t idx = (((size_t)rowblk * kSB + sblk) * 16 + lr) * 8;
    *reinterpret_cast<short8*>(zh + idx) = h;
    *reinterpret_cast<short8*>(zl + idx) = l;
}

// ---------------------------------------------------------------------------
__device__ __forceinline__ void load_a(
    const unsigned short* __restrict__ zhp, const unsigned short* __restrict__ zlp,
    int sblk0, short8 ah[4], short8 al[4])
{
    #pragma unroll
    for (int fm = 0; fm < 4; ++fm) {
        const size_t o = ((size_t)fm * kSB + sblk0) * 128;
        ah[fm] = *reinterpret_cast<const short8*>(zhp + o);
        al[fm] = *reinterpret_cast<const short8*>(zlp + o);
    }
}

__device__ __forceinline__ void load_b(const float* const bptr[4], int s0,
                                       float rb[4][8])
{
    #pragma unroll
    for (int fn = 0; fn < 4; ++fn)
        #pragma unroll
        for (int j = 0; j < 8; ++j)
            rb[fn][j] = bptr[fn][(size_t)(s0 + j) * 16];
}

__device__ __forceinline__ void step_mfma(
    const short8 ah[4], const short8 al[4], const float rb[4][8],
    f32x4 acc[4][4])
{
    #pragma unroll
    for (int fn = 0; fn < 4; ++fn) {
        short8 bh, bl;
        #pragma unroll
        for (int j = 0; j < 8; ++j) {
            const uint32_t u = __float_as_uint(rb[fn][j]);
            bh[j] = (short)(u >> 16);
            const float r = rb[fn][j] - __uint_as_float(u & 0xffff0000u);
            bl[j] = (short)(__float_as_uint(r) >> 16);
        }
        #pragma unroll
        for (int fm = 0; fm < 4; ++fm) {
            acc[fm][fn] = __builtin_amdgcn_mfma_f32_16x16x32_bf16(
                ah[fm], bh, acc[fm][fn], 0, 0, 0);
            acc[fm][fn] = __builtin_amdgcn_mfma_f32_16x16x32_bf16(
                ah[fm], bl, acc[fm][fn], 0, 0, 0);
            acc[fm][fn] = __builtin_amdgcn_mfma_f32_16x16x32_bf16(
                al[fm], bh, acc[fm][fn], 0, 0, 0);
        }
    }
}

// ---------------------------------------------------------------------------
// GEMM: vp[sk][b][col] partial over s-chunk sk. grid = 68*splitk 1-WAVE
// blocks: (sk, mt 0..3, cg 0..16); wave tile 64 rows x 64 cols (cg==16:
// core5, 16 cols). fm=fn=4, 16x16x32 bf16, 3-term split. No LDS/barriers;
// named double-buffer prefetch (hand-unrolled x2; nsteps is even).
// ---------------------------------------------------------------------------
__global__ __launch_bounds__(64, 2) void fttv_gemm_t(
    const unsigned short* __restrict__ zh, const unsigned short* __restrict__ zl,
    const float* __restrict__ c1, const float* __restrict__ c2,
    const float* __restrict__ c3, const float* __restrict__ c4,
    const float* __restrict__ c5,
    float* __restrict__ vp, int kc)
{
    // bijective XCD swizzle (m204); v = sk*68 + mt*17 + cg so co-resident
    // blocks share (sk, mt) -> A lines hit L1/L2.
    const int nwg = gridDim.x;
    const int q = nwg >> 3, r = nwg & 7;
    const int xcd = blockIdx.x & 7, rest = blockIdx.x >> 3;
    const int vfl = (xcd < r ? xcd * (q + 1) : r * (q + 1) + (xcd - r) * q) + rest;
    const int sk = vfl / 68;
    const int rem = vfl - sk * 68;
    const int mt = rem / 17;
    const int cg = rem - mt * 17;

    const int l = threadIdx.x;
    const int lr = l & 15, lkq = l >> 4;
    const int nsteps = kc >> 5;                 // even for splitk<=256
    const int sb00 = sk * (kc >> 3);            // absolute s-block base
    const int s0base = sk * kc + lkq * 8;       // absolute s base (lane)

    // A lane base: + (mt*4+fm)*kSB*128 + sblk*128 + lr*8
    const unsigned short* zhp = zh + ((size_t)(mt * 4) * kSB + lkq) * 128 + lr * 8;
    const unsigned short* zlp = zl + ((size_t)(mt * 4) * kSB + lkq) * 128 + lr * 8;

    f32x4 acc[4][4];
    #pragma unroll
    for (int i = 0; i < 4; ++i)
        #pragma unroll
        for (int j = 0; j < 4; ++j) acc[i][j] = (f32x4){0.f, 0.f, 0.f, 0.f};

    short8 ah0[4], al0[4], ah1[4], al1[4];

    if (cg < 16) {
        const int ci = cg >> 2;
        const float* cp = (ci == 0 ? c1 : ci == 1 ? c2 : ci == 2 ? c3 : c4);
        const int d0 = (cg & 3) * 4;
        const float* bptr[4];
        #pragma unroll
        for (int fn = 0; fn < 4; ++fn)
            bptr[fn] = cp + (size_t)(d0 + fn) * kS * 16 + lr;

        float rb0[4][8], rb1[4][8];
        load_a(zhp, zlp, sb00, ah0, al0);
        load_b(bptr, s0base, rb0);
        for (int t = 0; t < nsteps; t += 2) {
            load_a(zhp, zlp, sb00 + (t + 1) * 4, ah1, al1);
            load_b(bptr, s0base + (t + 1) * 32, rb1);
            step_mfma(ah0, al0, rb0, acc);
            if (t + 2 < nsteps) {
                load_a(zhp, zlp, sb00 + (t + 2) * 4, ah0, al0);
                load_b(bptr, s0base + (t + 2) * 32, rb0);
            }
            step_mfma(ah1, al1, rb1, acc);
        }
        // epilogue: C frag col=l&15, row=(l>>4)*4+qq
        #pragma unroll
        for (int fm = 0; fm < 4; ++fm)
            #pragma unroll
            for (int fn = 0; fn < 4; ++fn) {
                const int col = cg * 64 + fn * 16 + lr;
                const int brow = mt * 64 + fm * 16 + lkq * 4;
                #pragma unroll
                for (int qq = 0; qq < 4; ++qq)
                    vp[((size_t)sk * kB + brow + qq) * kNCol + col] =
                        acc[fm][fn][qq];
            }
    } else {
        // core5 runt: 16 cols; B lane loads 8 consecutive floats
        const float* bp5 = c5 + (size_t)lr * kS;
        float r50[8], r51[8];
        load_a(zhp, zlp, sb00, ah0, al0);
        *reinterpret_cast<float4*>(&r50[0]) =
            *reinterpret_cast<const float4*>(bp5 + s0base);
        *reinterpret_cast<float4*>(&r50[4]) =
            *reinterpret_cast<const float4*>(bp5 + s0base + 4);
        for (int t = 0; t < nsteps; t += 2) {
            load_a(zhp, zlp, sb00 + (t + 1) * 4, ah1, al1);
            *reinterpret_cast<float4*>(&r51[0]) =
                *reinterpret_cast<const float4*>(bp5 + s0base + (t + 1) * 32);
            *reinterpret_cast<float4*>(&r51[4]) =
                *reinterpret_cast<const float4*>(bp5 + s0base + (t + 1) * 32 + 4);
            {
                short8 bh, bl;
                #pragma unroll
                for (int j = 0; j < 8; ++j) {
                    const uint32_t u = __float_as_uint(r50[j]);
                    bh[j] = (short)(u >> 16);
                    const float rr = r50[j] - __uint_as_float(u & 0xffff0000u);
                    bl[j] = (short)(__float_as_uint(rr) >> 16);
                }
                #pragma unroll
                for (int fm = 0; fm < 4; ++fm) {
                    acc[fm][0] = __builtin_amdgcn_mfma_f32_16x16x32_bf16(
                        ah0[fm], bh, acc[fm][0], 0, 0, 0);
                    acc[fm][0] = __builtin_amdgcn_mfma_f32_16x16x32_bf16(
                        ah0[fm], bl, acc[fm][0], 0, 0, 0);
                    acc[fm][0] = __builtin_amdgcn_mfma_f32_16x16x32_bf16(
                        al0[fm], bh, acc[fm][0], 0, 0, 0);
                }
            }
            if (t + 2 < nsteps) {
                load_a(zhp, zlp, sb00 + (t + 2) * 4, ah0, al0);
                *reinterpret_cast<float4*>(&r50[0]) =
                    *reinterpret_cast<const float4*>(bp5 + s0base + (t + 2) * 32);
                *reinterpret_cast<float4*>(&r50[4]) =
                    *reinterpret_cast<const float4*>(bp5 + s0base + (t + 2) * 32 + 4);
            }
            {
                short8 bh, bl;
                #pragma unroll
                for (int j = 0; j < 8; ++j) {
                    const uint32_t u = __float_as_uint(r51[j]);
                    bh[j] = (short)(u >> 16);
                    const float rr = r51[j] - __uint_as_float(u & 0xffff0000u);
                    bl[j] = (short)(__float_as_uint(rr) >> 16);
                }
                #pragma unroll
                for (int fm = 0; fm < 4; ++fm) {
                    acc[fm][0] = __builtin_amdgcn_mfma_f32_16x16x32_bf16(
                        ah1[fm], bh, acc[fm][0], 0, 0, 0);
                    acc[fm][0] = __builtin_amdgcn_mfma_f32_16x16x32_bf16(
                        ah1[fm], bl, acc[fm][0], 0, 0, 0);
                    acc[fm][0] = __builtin_amdgcn_mfma_f32_16x16x32_bf16(
                        al1[fm], bh, acc[fm][0], 0, 0, 0);
                }
            }
        }
        #pragma unroll
        for (int fm = 0; fm < 4; ++fm) {
            const int col = 1024 + lr;
            const int brow = mt * 64 + fm * 16 + lkq * 4;
            #pragma unroll
            for (int qq = 0; qq < 4; ++qq)
                vp[((size_t)sk * kB + brow + qq) * kNCol + col] = acc[fm][0][qq];
        }
    }
}

// ---------------------------------------------------------------------------
// v[b][col] = sum_sk vp[sk][b][col]; float4, fully coalesced.
__global__ void fttv_reduce(const float* __restrict__ vp, float* __restrict__ v,
                            int splitk)
{
    const int i4 = blockIdx.x * 256 + threadIdx.x;
    float4 s = make_float4(0.f, 0.f, 0.f, 0.f);
    for (int k = 0; k < splitk; ++k) {
        const float4 t = *reinterpret_cast<const float4*>(
            vp + (size_t)k * kNCol * kB + (size_t)i4 * 4);
        s.x += t.x; s.y += t.y; s.z += t.z; s.w += t.w;
    }
    *reinterpret_cast<float4*>(v + (size_t)i4 * 4) = s;
}

// W[b] = V1@V2@V3@V4@V5col; one 64-thr block per batch; v layout [b][col]
__global__ void fttv_chain(const float* __restrict__ v, float* __restrict__ w)
{
    const int b = blockIdx.x;
    const float* vb = v + (size_t)b * kNCol;
    const int lane = threadIdx.x;
    const int d = lane & 15;
    float u = vb[1024 + d];
    #pragma unroll
    for (int k = 4; k >= 1; --k) {
        float nu = 0.f;
        #pragma unroll
        for (int e = 0; e < 16; ++e) {
            const float ue = __shfl(u, e, 16);
            nu += vb[(k - 1) * 256 + d * 16 + e] * ue;
        }
        u = nu;
    }
    if (lane < 16) w[b * 16 + d] = u;
}

// out[b,s] = sum_d c0[s,d] * W[b,d]
__global__ __launch_bounds__(256) void fttv_out(
    const float* __restrict__ c0, const float* __restrict__ w,
    float* __restrict__ out)
{
    __shared__ float wl[64][16];
    const int sc = blockIdx.x & 63;
    const int bq = blockIdx.x >> 6;
    const int tid = threadIdx.x;
    const int s = sc * 256 + tid;
    float f0[16];
    #pragma unroll
    for (int q = 0; q < 4; ++q)
        *reinterpret_cast<float4*>(&f0[q * 4]) =
            *reinterpret_cast<const float4*>(c0 + (size_t)s * 16 + q * 4);
    *reinterpret_cast<float4*>(&wl[0][0] + tid * 4) =
        *reinterpret_cast<const float4*>(w + bq * 1024 + tid * 4);
    __syncthreads();
    for (int bb = 0; bb < 64; ++bb) {
        float a = 0.f;
        #pragma unroll
        for (int d = 0; d < 16; ++d) a += f0[d] * wl[bb][d];
        out[(size_t)(bq * 64 + bb) * kS + s] = a;
    }
}

// ---------------------------------------------------------------------------
extern "C" void kernel_launch(void* const* d_in, const int* in_sizes, int n_in,
                              void* d_out, int out_size, void* d_ws, size_t ws_size,
                              hipStream_t stream)
{
    (void)in_sizes; (void)n_in; (void)out_size;
    const float* z  = (const float*)d_in[0];
    const float* c0 = (const float*)d_in[1];
    const float* c1 = (const float*)d_in[2];
    const float* c2 = (const float*)d_in[3];
    const float* c3 = (const float*)d_in[4];
    const float* c4 = (const float*)d_in[5];
    const float* c5 = (const float*)d_in[6];
    float* out = (float*)d_out;
    float* ws  = (float*)d_ws;

    // ws (f32 units): zh+zl (2 * 256*16384 bf16 = 4.19M f32) |
    //                 vp[splitk][256][1040] | v[256][1040] | w[256][16]
    const size_t zhlF = (size_t)kB * kS;   // both planes, in f32 units
    int splitk = 32;
    while (splitk > 1 &&
           (zhlF + (size_t)(splitk + 1) * kNCol * kB + (size_t)kB * 16)
               * sizeof(float) > ws_size)
        splitk >>= 1;
    const int kc = kS / splitk;

    unsigned short* zh = (unsigned short*)ws;
    unsigned short* zl = zh + (size_t)kB * kS;
    float* vp = ws + zhlF;
    float* v  = vp + (size_t)splitk * kNCol * kB;
    float* w  = v + (size_t)kNCol * kB;

    fttv_split<<<dim3((kB * kS / 8) / 256), 256, 0, stream>>>(z, zh, zl);
    fttv_gemm_t<<<dim3(68 * splitk), 64, 0, stream>>>(
        zh, zl, c1, c2, c3, c4, c5, vp, kc);
    fttv_reduce<<<dim3(kNCol * kB / 1024), 256, 0, stream>>>(vp, v, splitk);
    fttv_chain<<<dim3(kB), 64, 0, stream>>>(v, w);
    fttv_out<<<dim3(256), 256, 0, stream>>>(c0, w, out);
}